// Round 3
// baseline (379.300 us; speedup 1.0000x reference)
//
#include <hip/hip_runtime.h>
#include <hip/hip_bf16.h>

// QLoRA forward: out = x @ dequant(q_w, scales)^T + 2.0 * (x @ A^T) @ B^T
// M=8192, N=4096, K=4096, rank=16, group=64.
// GEMM: 256x256 tile, BK=32, 8 waves, triple-buffered LDS, counted vmcnt(4),
// 2-phase fine interleave per K-tile (16 MFMA per phase, T3+T4), bank-swizzle
// via pre-swizzled global source (T2), XCD swizzle (T1), setprio (T5).
// LoRA folded as 129th K-tile (rank 16 zero-padded to K=32).

typedef unsigned short u16;
typedef __attribute__((ext_vector_type(8))) short bf16x8;
typedef __attribute__((ext_vector_type(4))) float f32x4;

#define M_DIM 8192
#define N_DIM 4096
#define K_DIM 4096
#define BM 256
#define BN 256
#define BK 32
#define KT_MAIN 128
#define NT 129

// round-to-nearest-even f32 -> bf16
__device__ static inline u16 f2bf(float f) {
    union { float f; unsigned u; } v; v.f = f;
    unsigned r = v.u + 0x7fffu + ((v.u >> 16) & 1u);
    return (u16)(r >> 16);
}

__device__ static inline void gload16(const void* g, void* s) {
    __builtin_amdgcn_global_load_lds(
        (const __attribute__((address_space(1))) void*)g,
        (__attribute__((address_space(3))) void*)s, 16, 0, 0);
}

// ---------------- W dequant: Wb[o][k] = bf16(q[o][k] * scales[o][k/64]) -----
__global__ __launch_bounds__(256) void wprep_kernel(
        const int* __restrict__ q, const float* __restrict__ scales,
        u16* __restrict__ Wb) {
    int idx = blockIdx.x * 256 + threadIdx.x;
    int o  = idx >> 9;
    int kc = (idx & 511) << 3;
    float s = scales[(o << 6) + (kc >> 6)];
    const int4* qp = (const int4*)(q + (size_t)o * K_DIM + kc);
    int4 q0 = qp[0], q1 = qp[1];
    ushort4 r0, r1;
    r0.x = f2bf((float)q0.x * s); r0.y = f2bf((float)q0.y * s);
    r0.z = f2bf((float)q0.z * s); r0.w = f2bf((float)q0.w * s);
    r1.x = f2bf((float)q1.x * s); r1.y = f2bf((float)q1.y * s);
    r1.z = f2bf((float)q1.z * s); r1.w = f2bf((float)q1.w * s);
    *(ushort4*)&Wb[(size_t)o * K_DIM + kc]     = r0;
    *(ushort4*)&Wb[(size_t)o * K_DIM + kc + 4] = r1;
}

// ---------------- B2 pack: [4096][32] bf16, cols 16..31 = 0 ----------------
__global__ __launch_bounds__(256) void bprep_kernel(
        const float* __restrict__ lora_B, u16* __restrict__ B2) {
    int idx = blockIdx.x * 256 + threadIdx.x;
    int o = idx >> 5, r = idx & 31;
    B2[idx] = (r < 16) ? f2bf(lora_B[o * 16 + r]) : (u16)0;
}

// ---------------- x prep (fused): xb = bf16(x); t2 = bf16(2 * x @ A^T) -----
__global__ __launch_bounds__(256) void xprep_kernel(
        const float* __restrict__ x, const float* __restrict__ lora_A,
        u16* __restrict__ xb, u16* __restrict__ t2) {
    const int tid = threadIdx.x, w = tid >> 6, l = tid & 63;
    const int rb = blockIdx.x * 8 + w * 2;     // wave's 2 rows
    float acc[2][16];
#pragma unroll
    for (int j = 0; j < 2; ++j)
#pragma unroll
        for (int r = 0; r < 16; ++r) acc[j][r] = 0.f;

    for (int i = 0; i < 16; ++i) {
        int k0 = i * 256 + l * 4;
        float4 x0 = *(const float4*)&x[(size_t)rb * K_DIM + k0];
        float4 x1 = *(const float4*)&x[(size_t)(rb + 1) * K_DIM + k0];
        ushort4 o0, o1;
        o0.x = f2bf(x0.x); o0.y = f2bf(x0.y); o0.z = f2bf(x0.z); o0.w = f2bf(x0.w);
        o1.x = f2bf(x1.x); o1.y = f2bf(x1.y); o1.z = f2bf(x1.z); o1.w = f2bf(x1.w);
        *(ushort4*)&xb[(size_t)rb * K_DIM + k0]       = o0;
        *(ushort4*)&xb[(size_t)(rb + 1) * K_DIM + k0] = o1;
#pragma unroll
        for (int r = 0; r < 16; ++r) {
            float4 av = *(const float4*)&lora_A[(size_t)r * K_DIM + k0];
            acc[0][r] += x0.x * av.x + x0.y * av.y + x0.z * av.z + x0.w * av.w;
            acc[1][r] += x1.x * av.x + x1.y * av.y + x1.z * av.z + x1.w * av.w;
        }
    }
#pragma unroll
    for (int j = 0; j < 2; ++j)
#pragma unroll
        for (int r = 0; r < 16; ++r) {
            float v = acc[j][r];
            v += __shfl_xor(v, 32); v += __shfl_xor(v, 16);
            v += __shfl_xor(v, 8);  v += __shfl_xor(v, 4);
            v += __shfl_xor(v, 2);  v += __shfl_xor(v, 1);
            acc[j][r] = v;
        }
    float v = 0.f;
#pragma unroll
    for (int j = 0; j < 2; ++j)
#pragma unroll
        for (int r = 0; r < 16; ++r)
            if (l == j * 16 + r) v = acc[j][r];
    int row = (l >> 4) & 1, col = (l & 15) + ((l >= 32) ? 16 : 0);
    u16 outv = (l < 32) ? f2bf(2.0f * v) : (u16)0;   // cols 16..31 zero pad
    t2[(size_t)(rb + row) * 32 + col] = outv;
}

// ---------------- main GEMM ------------------------------------------------
// LDS per buf: A = 256x32 bf16 (16KB, bytes [0,16384)), B same ([16384,32768)).
// Swizzle: logical 16B-slot s of row r stored at phys slot s ^ ((r>>1)&3),
// achieved by pre-swizzling the gload SOURCE address (LDS dest stays linear).
__global__ __launch_bounds__(512, 2) void qlora_gemm(
        const u16* __restrict__ xb, const u16* __restrict__ Wb,
        const u16* __restrict__ t2, const u16* __restrict__ B2,
        float* __restrict__ out) {
    __shared__ u16 lds[3][16384];                 // 96 KB
    // XCD-aware bijective swizzle: 512 blocks = 8 XCDs x 64
    int bid = blockIdx.x;
    int swz = (bid & 7) * 64 + (bid >> 3);
    int bn = swz >> 5;                            // 0..15
    int bm = swz & 31;                            // 0..31
    const int tid = threadIdx.x, w = tid >> 6, l = tid & 63;
    const int wr = w >> 2, wc = w & 3;            // 2x4 wave grid, 128x64 per wave
    const int fr = l & 15, fq = l >> 4;
    const int sA = fq ^ ((fr >> 1) & 3);          // swizzled slot for frag reads

    // staging precompute: thread covers tile-row rs (q=0) and rs+128 (q=1)
    const int rs   = w * 16 + (l >> 2);
    const int sl16 = ((l & 3) ^ ((l >> 3) & 3)) << 4;   // pre-swizzled src k-offset
    const char* aRow0 = (const char*)xb + (((size_t)(bm * 256 + rs)) << 13) + sl16;
    const char* aRow1 = aRow0 + (size_t)(128u << 13);
    const char* bRow0 = (const char*)Wb + (((size_t)(bn * 256 + rs)) << 13) + sl16;
    const char* bRow1 = bRow0 + (size_t)(128u << 13);
    const char* aL0 = (const char*)t2 + (size_t)(bm * 256 + rs) * 64 + sl16;
    const char* aL1 = aL0 + 128 * 64;
    const char* bL0 = (const char*)B2 + (size_t)(bn * 256 + rs) * 64 + sl16;
    const char* bL1 = bL0 + 128 * 64;
    char* ldsC = (char*)&lds[0][0];
    const int dA = w * 1024;                      // wave-uniform LDS dest (+q*8192)
    const int dB = 16384 + w * 1024;

    // frag-read byte offsets (within a buffer)
    const int aoff = (wr * 128 + fr) * 64 + sA * 16;           // + i*1024
    const int boff = 16384 + (wc * 64 + fr) * 64 + sA * 16;    // + j*1024

    f32x4 acc[8][4] = {};

    auto stageA = [&](int kt, int buf) {          // A halves: 2 gloads
        char* base = ldsC + buf * 32768;
        if (kt < KT_MAIN) {
            size_t ko = (size_t)kt * 64;
            gload16(aRow0 + ko, base + dA);
            gload16(aRow1 + ko, base + dA + 8192);
        } else {
            gload16(aL0, base + dA);
            gload16(aL1, base + dA + 8192);
        }
    };
    auto stageB = [&](int kt, int buf) {          // B halves: 2 gloads
        char* base = ldsC + buf * 32768;
        if (kt < KT_MAIN) {
            size_t ko = (size_t)kt * 64;
            gload16(bRow0 + ko, base + dB);
            gload16(bRow1 + ko, base + dB + 8192);
        } else {
            gload16(bL0, base + dB);
            gload16(bL1, base + dB + 8192);
        }
    };

    stageA(0, 0); stageB(0, 0);
    stageA(1, 1); stageB(1, 1);
    asm volatile("s_waitcnt vmcnt(4)" ::: "memory");   // tile 0 landed
    __builtin_amdgcn_s_barrier();
    asm volatile("" ::: "memory");

    for (int t = 0; t < NT; ++t) {
        const char* cb = ldsC + (t % 3) * 32768;

        // ================= phase A: C rows 0..63 (i = 0..3) =================
        bf16x8 bfr[4], af[4];
#pragma unroll
        for (int j = 0; j < 4; ++j)
            bfr[j] = *(const bf16x8*)(cb + boff + j * 1024);
#pragma unroll
        for (int i = 0; i < 4; ++i)
            af[i] = *(const bf16x8*)(cb + aoff + i * 1024);
        __builtin_amdgcn_sched_barrier(0);
        if (t + 2 < NT) stageA(t + 2, (t + 2) % 3);    // buf nobody reads
        __builtin_amdgcn_s_barrier();
        asm volatile("s_waitcnt lgkmcnt(0)" ::: "memory");
        __builtin_amdgcn_sched_barrier(0);
        __builtin_amdgcn_s_setprio(1);
#pragma unroll
        for (int i = 0; i < 4; ++i)
#pragma unroll
            for (int j = 0; j < 4; ++j)
                acc[i][j] = __builtin_amdgcn_mfma_f32_16x16x32_bf16(
                                af[i], bfr[j], acc[i][j], 0, 0, 0);
        __builtin_amdgcn_s_setprio(0);
        __builtin_amdgcn_sched_barrier(0);
        __builtin_amdgcn_s_barrier();

        // ================= phase B: C rows 64..127 (i = 4..7) ===============
        bf16x8 af2[4];
#pragma unroll
        for (int i = 0; i < 4; ++i)
            af2[i] = *(const bf16x8*)(cb + aoff + (i + 4) * 1024);
        __builtin_amdgcn_sched_barrier(0);
        if (t + 2 < NT) stageB(t + 2, (t + 2) % 3);
        __builtin_amdgcn_s_barrier();
        asm volatile("s_waitcnt lgkmcnt(0)" ::: "memory");
        __builtin_amdgcn_sched_barrier(0);
        __builtin_amdgcn_s_setprio(1);
#pragma unroll
        for (int i = 0; i < 4; ++i)
#pragma unroll
            for (int j = 0; j < 4; ++j)
                acc[i + 4][j] = __builtin_amdgcn_mfma_f32_16x16x32_bf16(
                                    af2[i], bfr[j], acc[i + 4][j], 0, 0, 0);
        __builtin_amdgcn_s_setprio(0);
        __builtin_amdgcn_sched_barrier(0);
        if (t + 1 < NT) {
            if (t + 2 < NT)
                asm volatile("s_waitcnt vmcnt(4)" ::: "memory");  // t+1 landed, t+2 in flight
            else
                asm volatile("s_waitcnt vmcnt(0)" ::: "memory");  // tail drain
            __builtin_amdgcn_s_barrier();
            asm volatile("" ::: "memory");
        }
    }

    // epilogue: C/D layout col=lane&15, row=(lane>>4)*4+reg  [validated]
    float* obase = out + (size_t)(bm * 256 + wr * 128 + fq * 4) * N_DIM
                       + bn * 256 + wc * 64 + fr;
#pragma unroll
    for (int i = 0; i < 8; ++i)
#pragma unroll
        for (int j = 0; j < 4; ++j)
#pragma unroll
            for (int r = 0; r < 4; ++r)
                obase[(size_t)(i * 16 + r) * N_DIM + j * 16] = acc[i][j][r];
}

extern "C" void kernel_launch(void* const* d_in, const int* in_sizes, int n_in,
                              void* d_out, int out_size, void* d_ws, size_t ws_size,
                              hipStream_t stream) {
    const float* x      = (const float*)d_in[0];
    const int*   qw     = (const int*)d_in[1];
    const float* scales = (const float*)d_in[2];
    const float* lora_A = (const float*)d_in[3];
    const float* lora_B = (const float*)d_in[4];
    float* out = (float*)d_out;

    char* ws = (char*)d_ws;
    u16* xb = (u16*)(ws);                       // 8192*4096*2 = 67,108,864 B
    u16* Wb = (u16*)(ws + 67108864);            // 4096*4096*2 = 33,554,432 B
    u16* t2 = (u16*)(ws + 100663296);           // 8192*32*2   =    524,288 B
    u16* B2 = (u16*)(ws + 101187584);           // 4096*32*2   =    262,144 B

    wprep_kernel<<<8192, 256, 0, stream>>>(qw, scales, Wb);
    bprep_kernel<<<512, 256, 0, stream>>>(lora_B, B2);
    xprep_kernel<<<1024, 256, 0, stream>>>(x, lora_A, xb, t2);
    qlora_gemm<<<dim3(512), 512, 0, stream>>>(xb, Wb, t2, B2, out);
}

// Round 5
// 362.152 us; speedup vs baseline: 1.0473x; 1.0473x over previous
//
#include <hip/hip_runtime.h>
#include <hip/hip_bf16.h>

// QLoRA forward: out = x @ dequant(q_w, scales)^T + 2.0 * (x @ A^T) @ B^T
// M=8192, N=4096, K=4096, rank=16, group=64.
// GEMM: 256x256 tile, BK=32, 8 waves, triple-buffered LDS, counted vmcnt(4),
// 2-phase fine interleave per K-tile, bank-swizzle via pre-swizzled global
// source (conflicts measured 0), XCD swizzle, setprio.
// Round 5 (= r4 intent, compile-fixed): NON-TEMPORAL output stores + nt
// single-touch prep loads to stop the 134MB write stream from evicting the
// 100MB input set out of L3 (r3: FETCH 669MB on 100MB inputs = L3 thrash).
// Fix: __builtin_nontemporal_load needs ext_vector_type, not HIP int4/float4.

typedef unsigned short u16;
typedef __attribute__((ext_vector_type(8))) short bf16x8;
typedef __attribute__((ext_vector_type(4))) float f32x4;
typedef __attribute__((ext_vector_type(4))) int i32x4;

#define M_DIM 8192
#define N_DIM 4096
#define K_DIM 4096
#define BM 256
#define BN 256
#define BK 32
#define KT_MAIN 128
#define NT 129

// round-to-nearest-even f32 -> bf16
__device__ static inline u16 f2bf(float f) {
    union { float f; unsigned u; } v; v.f = f;
    unsigned r = v.u + 0x7fffu + ((v.u >> 16) & 1u);
    return (u16)(r >> 16);
}

__device__ static inline void gload16(const void* g, void* s) {
    __builtin_amdgcn_global_load_lds(
        (const __attribute__((address_space(1))) void*)g,
        (__attribute__((address_space(3))) void*)s, 16, 0, 0);
}

// ---------------- W dequant: Wb[o][k] = bf16(q[o][k] * scales[o][k/64]) -----
__global__ __launch_bounds__(256) void wprep_kernel(
        const int* __restrict__ q, const float* __restrict__ scales,
        u16* __restrict__ Wb) {
    int idx = blockIdx.x * 256 + threadIdx.x;
    int o  = idx >> 9;
    int kc = (idx & 511) << 3;
    float s = scales[(o << 6) + (kc >> 6)];
    const i32x4* qp = (const i32x4*)(q + (size_t)o * K_DIM + kc);
    i32x4 q0 = __builtin_nontemporal_load(qp);       // q read exactly once
    i32x4 q1 = __builtin_nontemporal_load(qp + 1);
    ushort4 r0, r1;
    r0.x = f2bf((float)q0.x * s); r0.y = f2bf((float)q0.y * s);
    r0.z = f2bf((float)q0.z * s); r0.w = f2bf((float)q0.w * s);
    r1.x = f2bf((float)q1.x * s); r1.y = f2bf((float)q1.y * s);
    r1.z = f2bf((float)q1.z * s); r1.w = f2bf((float)q1.w * s);
    *(ushort4*)&Wb[(size_t)o * K_DIM + kc]     = r0;
    *(ushort4*)&Wb[(size_t)o * K_DIM + kc + 4] = r1;
}

// ---------------- B2 pack: [4096][32] bf16, cols 16..31 = 0 ----------------
__global__ __launch_bounds__(256) void bprep_kernel(
        const float* __restrict__ lora_B, u16* __restrict__ B2) {
    int idx = blockIdx.x * 256 + threadIdx.x;
    int o = idx >> 5, r = idx & 31;
    B2[idx] = (r < 16) ? f2bf(lora_B[o * 16 + r]) : (u16)0;
}

// ---------------- x prep (fused): xb = bf16(x); t2 = bf16(2 * x @ A^T) -----
__global__ __launch_bounds__(256) void xprep_kernel(
        const float* __restrict__ x, const float* __restrict__ lora_A,
        u16* __restrict__ xb, u16* __restrict__ t2) {
    const int tid = threadIdx.x, w = tid >> 6, l = tid & 63;
    const int rb = blockIdx.x * 8 + w * 2;     // wave's 2 rows
    float acc[2][16];
#pragma unroll
    for (int j = 0; j < 2; ++j)
#pragma unroll
        for (int r = 0; r < 16; ++r) acc[j][r] = 0.f;

    for (int i = 0; i < 16; ++i) {
        int k0 = i * 256 + l * 4;
        f32x4 x0 = __builtin_nontemporal_load(
                        (const f32x4*)&x[(size_t)rb * K_DIM + k0]);
        f32x4 x1 = __builtin_nontemporal_load(
                        (const f32x4*)&x[(size_t)(rb + 1) * K_DIM + k0]);
        ushort4 o0, o1;
        o0.x = f2bf(x0.x); o0.y = f2bf(x0.y); o0.z = f2bf(x0.z); o0.w = f2bf(x0.w);
        o1.x = f2bf(x1.x); o1.y = f2bf(x1.y); o1.z = f2bf(x1.z); o1.w = f2bf(x1.w);
        *(ushort4*)&xb[(size_t)rb * K_DIM + k0]       = o0;
        *(ushort4*)&xb[(size_t)(rb + 1) * K_DIM + k0] = o1;
#pragma unroll
        for (int r = 0; r < 16; ++r) {
            f32x4 av = *(const f32x4*)&lora_A[(size_t)r * K_DIM + k0];
            acc[0][r] += x0.x * av.x + x0.y * av.y + x0.z * av.z + x0.w * av.w;
            acc[1][r] += x1.x * av.x + x1.y * av.y + x1.z * av.z + x1.w * av.w;
        }
    }
#pragma unroll
    for (int j = 0; j < 2; ++j)
#pragma unroll
        for (int r = 0; r < 16; ++r) {
            float v = acc[j][r];
            v += __shfl_xor(v, 32); v += __shfl_xor(v, 16);
            v += __shfl_xor(v, 8);  v += __shfl_xor(v, 4);
            v += __shfl_xor(v, 2);  v += __shfl_xor(v, 1);
            acc[j][r] = v;
        }
    float v = 0.f;
#pragma unroll
    for (int j = 0; j < 2; ++j)
#pragma unroll
        for (int r = 0; r < 16; ++r)
            if (l == j * 16 + r) v = acc[j][r];
    int row = (l >> 4) & 1, col = (l & 15) + ((l >= 32) ? 16 : 0);
    u16 outv = (l < 32) ? f2bf(2.0f * v) : (u16)0;   // cols 16..31 zero pad
    t2[(size_t)(rb + row) * 32 + col] = outv;
}

// ---------------- main GEMM ------------------------------------------------
// LDS per buf: A = 256x32 bf16 (16KB, bytes [0,16384)), B same ([16384,32768)).
// Swizzle: logical 16B-slot s of row r stored at phys slot s ^ ((r>>1)&3),
// achieved by pre-swizzling the gload SOURCE address (LDS dest stays linear).
__global__ __launch_bounds__(512, 2) void qlora_gemm(
        const u16* __restrict__ xb, const u16* __restrict__ Wb,
        const u16* __restrict__ t2, const u16* __restrict__ B2,
        float* __restrict__ out) {
    __shared__ u16 lds[3][16384];                 // 96 KB
    // XCD-aware bijective swizzle: 512 blocks = 8 XCDs x 64
    int bid = blockIdx.x;
    int swz = (bid & 7) * 64 + (bid >> 3);
    int bn = swz >> 5;                            // 0..15
    int bm = swz & 31;                            // 0..31
    const int tid = threadIdx.x, w = tid >> 6, l = tid & 63;
    const int wr = w >> 2, wc = w & 3;            // 2x4 wave grid, 128x64 per wave
    const int fr = l & 15, fq = l >> 4;
    const int sA = fq ^ ((fr >> 1) & 3);          // swizzled slot for frag reads

    // staging precompute: thread covers tile-row rs (q=0) and rs+128 (q=1)
    const int rs   = w * 16 + (l >> 2);
    const int sl16 = ((l & 3) ^ ((l >> 3) & 3)) << 4;   // pre-swizzled src k-offset
    const char* aRow0 = (const char*)xb + (((size_t)(bm * 256 + rs)) << 13) + sl16;
    const char* aRow1 = aRow0 + (size_t)(128u << 13);
    const char* bRow0 = (const char*)Wb + (((size_t)(bn * 256 + rs)) << 13) + sl16;
    const char* bRow1 = bRow0 + (size_t)(128u << 13);
    const char* aL0 = (const char*)t2 + (size_t)(bm * 256 + rs) * 64 + sl16;
    const char* aL1 = aL0 + 128 * 64;
    const char* bL0 = (const char*)B2 + (size_t)(bn * 256 + rs) * 64 + sl16;
    const char* bL1 = bL0 + 128 * 64;
    char* ldsC = (char*)&lds[0][0];
    const int dA = w * 1024;                      // wave-uniform LDS dest (+q*8192)
    const int dB = 16384 + w * 1024;

    // frag-read byte offsets (within a buffer)
    const int aoff = (wr * 128 + fr) * 64 + sA * 16;           // + i*1024
    const int boff = 16384 + (wc * 64 + fr) * 64 + sA * 16;    // + j*1024

    f32x4 acc[8][4] = {};

    auto stageA = [&](int kt, int buf) {          // A halves: 2 gloads
        char* base = ldsC + buf * 32768;
        if (kt < KT_MAIN) {
            size_t ko = (size_t)kt * 64;
            gload16(aRow0 + ko, base + dA);
            gload16(aRow1 + ko, base + dA + 8192);
        } else {
            gload16(aL0, base + dA);
            gload16(aL1, base + dA + 8192);
        }
    };
    auto stageB = [&](int kt, int buf) {          // B halves: 2 gloads
        char* base = ldsC + buf * 32768;
        if (kt < KT_MAIN) {
            size_t ko = (size_t)kt * 64;
            gload16(bRow0 + ko, base + dB);
            gload16(bRow1 + ko, base + dB + 8192);
        } else {
            gload16(bL0, base + dB);
            gload16(bL1, base + dB + 8192);
        }
    };

    stageA(0, 0); stageB(0, 0);
    stageA(1, 1); stageB(1, 1);
    asm volatile("s_waitcnt vmcnt(4)" ::: "memory");   // tile 0 landed
    __builtin_amdgcn_s_barrier();
    asm volatile("" ::: "memory");

    for (int t = 0; t < NT; ++t) {
        const char* cb = ldsC + (t % 3) * 32768;

        // ================= phase A: C rows 0..63 (i = 0..3) =================
        bf16x8 bfr[4], af[4];
#pragma unroll
        for (int j = 0; j < 4; ++j)
            bfr[j] = *(const bf16x8*)(cb + boff + j * 1024);
#pragma unroll
        for (int i = 0; i < 4; ++i)
            af[i] = *(const bf16x8*)(cb + aoff + i * 1024);
        __builtin_amdgcn_sched_barrier(0);
        if (t + 2 < NT) stageA(t + 2, (t + 2) % 3);    // buf nobody reads
        __builtin_amdgcn_s_barrier();
        asm volatile("s_waitcnt lgkmcnt(0)" ::: "memory");
        __builtin_amdgcn_sched_barrier(0);
        __builtin_amdgcn_s_setprio(1);
#pragma unroll
        for (int i = 0; i < 4; ++i)
#pragma unroll
            for (int j = 0; j < 4; ++j)
                acc[i][j] = __builtin_amdgcn_mfma_f32_16x16x32_bf16(
                                af[i], bfr[j], acc[i][j], 0, 0, 0);
        __builtin_amdgcn_s_setprio(0);
        __builtin_amdgcn_sched_barrier(0);
        __builtin_amdgcn_s_barrier();

        // ================= phase B: C rows 64..127 (i = 4..7) ===============
        bf16x8 af2[4];
#pragma unroll
        for (int i = 0; i < 4; ++i)
            af2[i] = *(const bf16x8*)(cb + aoff + (i + 4) * 1024);
        __builtin_amdgcn_sched_barrier(0);
        if (t + 2 < NT) stageB(t + 2, (t + 2) % 3);
        __builtin_amdgcn_s_barrier();
        asm volatile("s_waitcnt lgkmcnt(0)" ::: "memory");
        __builtin_amdgcn_sched_barrier(0);
        __builtin_amdgcn_s_setprio(1);
#pragma unroll
        for (int i = 0; i < 4; ++i)
#pragma unroll
            for (int j = 0; j < 4; ++j)
                acc[i + 4][j] = __builtin_amdgcn_mfma_f32_16x16x32_bf16(
                                    af2[i], bfr[j], acc[i + 4][j], 0, 0, 0);
        __builtin_amdgcn_s_setprio(0);
        __builtin_amdgcn_sched_barrier(0);
        if (t + 1 < NT) {
            if (t + 2 < NT)
                asm volatile("s_waitcnt vmcnt(4)" ::: "memory");  // t+1 landed, t+2 in flight
            else
                asm volatile("s_waitcnt vmcnt(0)" ::: "memory");  // tail drain
            __builtin_amdgcn_s_barrier();
            asm volatile("" ::: "memory");
        }
    }

    // epilogue: C/D layout col=lane&15, row=(lane>>4)*4+reg  [validated]
    // NON-TEMPORAL stores: output is write-once -> don't evict inputs from L3.
    float* obase = out + (size_t)(bm * 256 + wr * 128 + fq * 4) * N_DIM
                       + bn * 256 + wc * 64 + fr;
#pragma unroll
    for (int i = 0; i < 8; ++i)
#pragma unroll
        for (int j = 0; j < 4; ++j)
#pragma unroll
            for (int r = 0; r < 4; ++r)
                __builtin_nontemporal_store(
                    acc[i][j][r],
                    &obase[(size_t)(i * 16 + r) * N_DIM + j * 16]);
}

extern "C" void kernel_launch(void* const* d_in, const int* in_sizes, int n_in,
                              void* d_out, int out_size, void* d_ws, size_t ws_size,
                              hipStream_t stream) {
    const float* x      = (const float*)d_in[0];
    const int*   qw     = (const int*)d_in[1];
    const float* scales = (const float*)d_in[2];
    const float* lora_A = (const float*)d_in[3];
    const float* lora_B = (const float*)d_in[4];
    float* out = (float*)d_out;

    char* ws = (char*)d_ws;
    u16* xb = (u16*)(ws);                       // 8192*4096*2 = 67,108,864 B
    u16* Wb = (u16*)(ws + 67108864);            // 4096*4096*2 = 33,554,432 B
    u16* t2 = (u16*)(ws + 100663296);           // 8192*32*2   =    524,288 B
    u16* B2 = (u16*)(ws + 101187584);           // 4096*32*2   =    262,144 B

    wprep_kernel<<<8192, 256, 0, stream>>>(qw, scales, Wb);
    bprep_kernel<<<512, 256, 0, stream>>>(lora_B, B2);
    xprep_kernel<<<1024, 256, 0, stream>>>(x, lora_A, xb, t2);
    qlora_gemm<<<dim3(512), 512, 0, stream>>>(xb, Wb, t2, B2, out);
}

// Round 6
// 321.974 us; speedup vs baseline: 1.1780x; 1.1248x over previous
//
#include <hip/hip_runtime.h>
#include <hip/hip_bf16.h>

// QLoRA forward: out = x @ dequant(q_w, scales)^T + 2.0 * (x @ A^T) @ B^T
// M=8192, N=4096, K=4096, rank=16, group=64.
// Round 6: BK=64, one barrier + one vmcnt per K-tile, all 8 stage-gloads
// issued at iteration top (issue->wait distance ~ full K-tile >> L3 latency),
// 2x64KB LDS double-buffer, 3-bit XOR bank swizzle via pre-swizzled source,
// XCD swizzle, setprio. LoRA folded as 65th K-tile (rank 16 padded to 64).

typedef unsigned short u16;
typedef __attribute__((ext_vector_type(8))) short bf16x8;
typedef __attribute__((ext_vector_type(4))) float f32x4;
typedef __attribute__((ext_vector_type(4))) int i32x4;

#define M_DIM 8192
#define N_DIM 4096
#define K_DIM 4096
#define BK 64
#define KT_MAIN 64
#define NT 65

// round-to-nearest-even f32 -> bf16
__device__ static inline u16 f2bf(float f) {
    union { float f; unsigned u; } v; v.f = f;
    unsigned r = v.u + 0x7fffu + ((v.u >> 16) & 1u);
    return (u16)(r >> 16);
}

__device__ static inline void gload16(const void* g, void* s) {
    __builtin_amdgcn_global_load_lds(
        (const __attribute__((address_space(1))) void*)g,
        (__attribute__((address_space(3))) void*)s, 16, 0, 0);
}

// ---------------- W dequant: Wb[o][k] = bf16(q[o][k] * scales[o][k/64]) -----
__global__ __launch_bounds__(256) void wprep_kernel(
        const int* __restrict__ q, const float* __restrict__ scales,
        u16* __restrict__ Wb) {
    int idx = blockIdx.x * 256 + threadIdx.x;
    int o  = idx >> 9;
    int kc = (idx & 511) << 3;
    float s = scales[(o << 6) + (kc >> 6)];
    const i32x4* qp = (const i32x4*)(q + (size_t)o * K_DIM + kc);
    i32x4 q0 = __builtin_nontemporal_load(qp);       // q read exactly once
    i32x4 q1 = __builtin_nontemporal_load(qp + 1);
    ushort4 r0, r1;
    r0.x = f2bf((float)q0.x * s); r0.y = f2bf((float)q0.y * s);
    r0.z = f2bf((float)q0.z * s); r0.w = f2bf((float)q0.w * s);
    r1.x = f2bf((float)q1.x * s); r1.y = f2bf((float)q1.y * s);
    r1.z = f2bf((float)q1.z * s); r1.w = f2bf((float)q1.w * s);
    *(ushort4*)&Wb[(size_t)o * K_DIM + kc]     = r0;
    *(ushort4*)&Wb[(size_t)o * K_DIM + kc + 4] = r1;
}

// ---------------- B2 pack: [4096][64] bf16, cols 16..63 = 0 ----------------
__global__ __launch_bounds__(256) void bprep_kernel(
        const float* __restrict__ lora_B, u16* __restrict__ B2) {
    int idx = blockIdx.x * 256 + threadIdx.x;   // 4096*64
    int o = idx >> 6, r = idx & 63;
    B2[idx] = (r < 16) ? f2bf(lora_B[o * 16 + r]) : (u16)0;
}

// ---------------- x prep (fused): xb = bf16(x); t2 = bf16(2 * x @ A^T) -----
// t2 is [8192][64], cols 16..63 zero.
__global__ __launch_bounds__(256) void xprep_kernel(
        const float* __restrict__ x, const float* __restrict__ lora_A,
        u16* __restrict__ xb, u16* __restrict__ t2) {
    const int tid = threadIdx.x, w = tid >> 6, l = tid & 63;
    const int rb = blockIdx.x * 8 + w * 2;     // wave's 2 rows
    float acc[2][16];
#pragma unroll
    for (int j = 0; j < 2; ++j)
#pragma unroll
        for (int r = 0; r < 16; ++r) acc[j][r] = 0.f;

    for (int i = 0; i < 16; ++i) {
        int k0 = i * 256 + l * 4;
        f32x4 x0 = __builtin_nontemporal_load(
                        (const f32x4*)&x[(size_t)rb * K_DIM + k0]);
        f32x4 x1 = __builtin_nontemporal_load(
                        (const f32x4*)&x[(size_t)(rb + 1) * K_DIM + k0]);
        ushort4 o0, o1;
        o0.x = f2bf(x0.x); o0.y = f2bf(x0.y); o0.z = f2bf(x0.z); o0.w = f2bf(x0.w);
        o1.x = f2bf(x1.x); o1.y = f2bf(x1.y); o1.z = f2bf(x1.z); o1.w = f2bf(x1.w);
        *(ushort4*)&xb[(size_t)rb * K_DIM + k0]       = o0;
        *(ushort4*)&xb[(size_t)(rb + 1) * K_DIM + k0] = o1;
#pragma unroll
        for (int r = 0; r < 16; ++r) {
            f32x4 av = *(const f32x4*)&lora_A[(size_t)r * K_DIM + k0];
            acc[0][r] += x0.x * av.x + x0.y * av.y + x0.z * av.z + x0.w * av.w;
            acc[1][r] += x1.x * av.x + x1.y * av.y + x1.z * av.z + x1.w * av.w;
        }
    }
#pragma unroll
    for (int j = 0; j < 2; ++j)
#pragma unroll
        for (int r = 0; r < 16; ++r) {
            float v = acc[j][r];
            v += __shfl_xor(v, 32); v += __shfl_xor(v, 16);
            v += __shfl_xor(v, 8);  v += __shfl_xor(v, 4);
            v += __shfl_xor(v, 2);  v += __shfl_xor(v, 1);
            acc[j][r] = v;   // every lane now holds the full reduced value
        }
    // t2 row pair-write: lane l -> row rb+(l>>5), col pair cp=(l&31)
    float lo = 0.f, hi = 0.f;
#pragma unroll
    for (int j = 0; j < 2; ++j)
#pragma unroll
        for (int c = 0; c < 8; ++c)
            if (l == j * 32 + c) { lo = acc[j][2 * c]; hi = acc[j][2 * c + 1]; }
    unsigned pack = (unsigned)f2bf(2.0f * lo) | ((unsigned)f2bf(2.0f * hi) << 16);
    *(unsigned*)&t2[(size_t)(rb + (l >> 5)) * 64 + (l & 31) * 2] = pack;
}

// ---------------- main GEMM ------------------------------------------------
// 256x256 tile, BK=64, 8 waves (2x4), LDS 2 bufs x (A 32KB + B 32KB) = 128KB.
// Row = 128B = 8 slots of 16B. Swizzle: phys slot p of row r holds logical
// slot p ^ (r&7); achieved by pre-swizzling the gload SOURCE (dest linear).
__global__ __launch_bounds__(512, 2) void qlora_gemm(
        const u16* __restrict__ xb, const u16* __restrict__ Wb,
        const u16* __restrict__ t2, const u16* __restrict__ B2,
        float* __restrict__ out) {
    __shared__ u16 lds[2][32768];                 // 128 KB
    // XCD-aware bijective swizzle: 512 blocks = 8 XCDs x 64
    int bid = blockIdx.x;
    int swz = (bid & 7) * 64 + (bid >> 3);
    int bn = swz >> 5;                            // 0..15
    int bm = swz & 31;                            // 0..31
    const int tid = threadIdx.x, w = tid >> 6, l = tid & 63;
    const int wr = w >> 2, wc = w & 3;            // 2x4 wave grid, 128x64 per wave
    const int fr = l & 15, fq = l >> 4;
    const int s0 = fq ^ (fr & 7);                 // swizzled slot, kk=0
    // (kk=1 slot = s0 ^ 4)

    // ---- staging addresses: op o covers tile rows o*64 + w*8 + (l>>3) ----
    const int sw16 = ((l & 7) ^ ((l >> 3) & 7)) << 4;   // pre-swizzled src offset
    const int rl   = w * 8 + (l >> 3);                  // row within op-0 stripe
    size_t offA[4], offB[4], lOffA[4], lOffB[4];
#pragma unroll
    for (int o = 0; o < 4; ++o) {
        int rA = bm * 256 + o * 64 + rl;
        int rB = bn * 256 + o * 64 + rl;
        offA[o]  = (size_t)rA * 8192 + sw16;      // xb: 4096 cols * 2B rows
        offB[o]  = (size_t)rB * 8192 + sw16;      // Wb
        lOffA[o] = (size_t)rA * 128 + sw16;       // t2: 64 cols * 2B rows
        lOffB[o] = (size_t)rB * 128 + sw16;       // B2
    }
    char* ldsC = (char*)&lds[0][0];
    const int dst = w * 1024 + l * 16;            // + o*8192 (A), +32768 (B)

    // ---- fragment-read byte offsets -------------------------------------
    const int arow = (wr * 128 + fr) * 128;              // + i*2048 + slot*16
    const int brow = 32768 + (wc * 64 + fr) * 128;       // + j*2048 + slot*16

    f32x4 acc[8][4] = {};

    auto stage = [&](int kt, int buf) {           // 8 gloads: full 64KB tile
        char* base = ldsC + buf * 65536;
        if (kt < KT_MAIN) {
            size_t ko = (size_t)kt * 128;
#pragma unroll
            for (int o = 0; o < 4; ++o) {
                gload16((const char*)xb + offA[o] + ko, base + dst + o * 8192);
                gload16((const char*)Wb + offB[o] + ko, base + 32768 + dst + o * 8192);
            }
        } else {                                  // lora tile
#pragma unroll
            for (int o = 0; o < 4; ++o) {
                gload16((const char*)t2 + lOffA[o], base + dst + o * 8192);
                gload16((const char*)B2 + lOffB[o], base + 32768 + dst + o * 8192);
            }
        }
    };

    stage(0, 0);
    asm volatile("s_waitcnt vmcnt(0)" ::: "memory");
    __builtin_amdgcn_s_barrier();
    asm volatile("" ::: "memory");

    for (int t = 0; t < NT; ++t) {
        const char* cb = ldsC + (t & 1) * 65536;
        if (t + 1 < NT) stage(t + 1, (t + 1) & 1);   // issue ALL next-tile loads now

        // kk = 0 half (cols 0..31)
        bf16x8 a0[8], b0[4];
#pragma unroll
        for (int j = 0; j < 4; ++j)
            b0[j] = *(const bf16x8*)(cb + brow + j * 2048 + s0 * 16);
#pragma unroll
        for (int i = 0; i < 8; ++i)
            a0[i] = *(const bf16x8*)(cb + arow + i * 2048 + s0 * 16);
        __builtin_amdgcn_s_setprio(1);
#pragma unroll
        for (int i = 0; i < 8; ++i)
#pragma unroll
            for (int j = 0; j < 4; ++j)
                acc[i][j] = __builtin_amdgcn_mfma_f32_16x16x32_bf16(
                                a0[i], b0[j], acc[i][j], 0, 0, 0);
        __builtin_amdgcn_s_setprio(0);

        // kk = 1 half (cols 32..63); slot = s0 ^ 4
        bf16x8 a1[8], b1[4];
#pragma unroll
        for (int j = 0; j < 4; ++j)
            b1[j] = *(const bf16x8*)(cb + brow + j * 2048 + (s0 ^ 4) * 16);
#pragma unroll
        for (int i = 0; i < 8; ++i)
            a1[i] = *(const bf16x8*)(cb + arow + i * 2048 + (s0 ^ 4) * 16);
        __builtin_amdgcn_s_setprio(1);
#pragma unroll
        for (int i = 0; i < 8; ++i)
#pragma unroll
            for (int j = 0; j < 4; ++j)
                acc[i][j] = __builtin_amdgcn_mfma_f32_16x16x32_bf16(
                                a1[i], b1[j], acc[i][j], 0, 0, 0);
        __builtin_amdgcn_s_setprio(0);

        if (t + 1 < NT) {
            // next tile's loads were issued ~a full K-tile ago -> cheap drain
            asm volatile("s_waitcnt vmcnt(0)" ::: "memory");
            __builtin_amdgcn_s_barrier();
            asm volatile("" ::: "memory");
        }
    }

    // epilogue: C/D layout col=lane&15, row=(lane>>4)*4+reg  [validated]
    float* obase = out + (size_t)(bm * 256 + wr * 128 + fq * 4) * N_DIM
                       + bn * 256 + wc * 64 + fr;
#pragma unroll
    for (int i = 0; i < 8; ++i)
#pragma unroll
        for (int j = 0; j < 4; ++j)
#pragma unroll
            for (int r = 0; r < 4; ++r)
                obase[(size_t)(i * 16 + r) * N_DIM + j * 16] = acc[i][j][r];
}

extern "C" void kernel_launch(void* const* d_in, const int* in_sizes, int n_in,
                              void* d_out, int out_size, void* d_ws, size_t ws_size,
                              hipStream_t stream) {
    const float* x      = (const float*)d_in[0];
    const int*   qw     = (const int*)d_in[1];
    const float* scales = (const float*)d_in[2];
    const float* lora_A = (const float*)d_in[3];
    const float* lora_B = (const float*)d_in[4];
    float* out = (float*)d_out;

    char* ws = (char*)d_ws;
    u16* xb = (u16*)(ws);                       // 8192*4096*2 = 67,108,864 B
    u16* Wb = (u16*)(ws + 67108864);            // 4096*4096*2 = 33,554,432 B
    u16* t2 = (u16*)(ws + 100663296);           // 8192*64*2   =  1,048,576 B
    u16* B2 = (u16*)(ws + 101711872);           // 4096*64*2   =    524,288 B

    wprep_kernel<<<8192, 256, 0, stream>>>(qw, scales, Wb);
    bprep_kernel<<<1024, 256, 0, stream>>>(lora_B, B2);
    xprep_kernel<<<1024, 256, 0, stream>>>(x, lora_A, xb, t2);
    qlora_gemm<<<dim3(512), 512, 0, stream>>>(xb, Wb, t2, B2, out);
}

// Round 7
// 313.252 us; speedup vs baseline: 1.2108x; 1.0278x over previous
//
#include <hip/hip_runtime.h>
#include <hip/hip_bf16.h>

// QLoRA forward: out = x @ dequant(q_w, scales)^T + 2.0 * (x @ A^T) @ B^T
// M=8192, N=4096, K=4096, rank=16, group=64.
// Round 7: r6 base (BK=64, 2x64KB dbuf, 1 barrier/tile, XOR swizzle, XCD
// swizzle) + REGISTER-PIPELINED frag reads: kk1 ds_reads + next-tile gloads
// issue before kk0 MFMA cluster; next-tile kk0 ds_reads issue before kk1
// MFMA cluster. Overlaps the ~2260cyc/tile LDS-read drain with the
// ~2483cyc/tile MFMA burst (r6 ran them serialized: 51% MfmaUtil = 2483/4523).

typedef unsigned short u16;
typedef __attribute__((ext_vector_type(8))) short bf16x8;
typedef __attribute__((ext_vector_type(4))) float f32x4;
typedef __attribute__((ext_vector_type(4))) int i32x4;

#define M_DIM 8192
#define N_DIM 4096
#define K_DIM 4096
#define BK 64
#define KT_MAIN 64
#define NT 65

// round-to-nearest-even f32 -> bf16
__device__ static inline u16 f2bf(float f) {
    union { float f; unsigned u; } v; v.f = f;
    unsigned r = v.u + 0x7fffu + ((v.u >> 16) & 1u);
    return (u16)(r >> 16);
}

__device__ static inline void gload16(const void* g, void* s) {
    __builtin_amdgcn_global_load_lds(
        (const __attribute__((address_space(1))) void*)g,
        (__attribute__((address_space(3))) void*)s, 16, 0, 0);
}

// ---------------- W dequant: Wb[o][k] = bf16(q[o][k] * scales[o][k/64]) -----
__global__ __launch_bounds__(256) void wprep_kernel(
        const int* __restrict__ q, const float* __restrict__ scales,
        u16* __restrict__ Wb) {
    int idx = blockIdx.x * 256 + threadIdx.x;
    int o  = idx >> 9;
    int kc = (idx & 511) << 3;
    float s = scales[(o << 6) + (kc >> 6)];
    const i32x4* qp = (const i32x4*)(q + (size_t)o * K_DIM + kc);
    i32x4 q0 = __builtin_nontemporal_load(qp);       // q read exactly once
    i32x4 q1 = __builtin_nontemporal_load(qp + 1);
    ushort4 r0, r1;
    r0.x = f2bf((float)q0.x * s); r0.y = f2bf((float)q0.y * s);
    r0.z = f2bf((float)q0.z * s); r0.w = f2bf((float)q0.w * s);
    r1.x = f2bf((float)q1.x * s); r1.y = f2bf((float)q1.y * s);
    r1.z = f2bf((float)q1.z * s); r1.w = f2bf((float)q1.w * s);
    *(ushort4*)&Wb[(size_t)o * K_DIM + kc]     = r0;
    *(ushort4*)&Wb[(size_t)o * K_DIM + kc + 4] = r1;
}

// ---------------- B2 pack: [4096][64] bf16, cols 16..63 = 0 ----------------
__global__ __launch_bounds__(256) void bprep_kernel(
        const float* __restrict__ lora_B, u16* __restrict__ B2) {
    int idx = blockIdx.x * 256 + threadIdx.x;   // 4096*64
    int o = idx >> 6, r = idx & 63;
    B2[idx] = (r < 16) ? f2bf(lora_B[o * 16 + r]) : (u16)0;
}

// ---------------- x prep (fused): xb = bf16(x); t2 = bf16(2 * x @ A^T) -----
// t2 is [8192][64], cols 16..63 zero.
__global__ __launch_bounds__(256) void xprep_kernel(
        const float* __restrict__ x, const float* __restrict__ lora_A,
        u16* __restrict__ xb, u16* __restrict__ t2) {
    const int tid = threadIdx.x, w = tid >> 6, l = tid & 63;
    const int rb = blockIdx.x * 8 + w * 2;     // wave's 2 rows
    float acc[2][16];
#pragma unroll
    for (int j = 0; j < 2; ++j)
#pragma unroll
        for (int r = 0; r < 16; ++r) acc[j][r] = 0.f;

    for (int i = 0; i < 16; ++i) {
        int k0 = i * 256 + l * 4;
        f32x4 x0 = __builtin_nontemporal_load(
                        (const f32x4*)&x[(size_t)rb * K_DIM + k0]);
        f32x4 x1 = __builtin_nontemporal_load(
                        (const f32x4*)&x[(size_t)(rb + 1) * K_DIM + k0]);
        ushort4 o0, o1;
        o0.x = f2bf(x0.x); o0.y = f2bf(x0.y); o0.z = f2bf(x0.z); o0.w = f2bf(x0.w);
        o1.x = f2bf(x1.x); o1.y = f2bf(x1.y); o1.z = f2bf(x1.z); o1.w = f2bf(x1.w);
        *(ushort4*)&xb[(size_t)rb * K_DIM + k0]       = o0;
        *(ushort4*)&xb[(size_t)(rb + 1) * K_DIM + k0] = o1;
#pragma unroll
        for (int r = 0; r < 16; ++r) {
            f32x4 av = *(const f32x4*)&lora_A[(size_t)r * K_DIM + k0];
            acc[0][r] += x0.x * av.x + x0.y * av.y + x0.z * av.z + x0.w * av.w;
            acc[1][r] += x1.x * av.x + x1.y * av.y + x1.z * av.z + x1.w * av.w;
        }
    }
#pragma unroll
    for (int j = 0; j < 2; ++j)
#pragma unroll
        for (int r = 0; r < 16; ++r) {
            float v = acc[j][r];
            v += __shfl_xor(v, 32); v += __shfl_xor(v, 16);
            v += __shfl_xor(v, 8);  v += __shfl_xor(v, 4);
            v += __shfl_xor(v, 2);  v += __shfl_xor(v, 1);
            acc[j][r] = v;   // every lane now holds the full reduced value
        }
    // t2 row pair-write: lane l -> row rb+(l>>5), col pair cp=(l&31)
    float lo = 0.f, hi = 0.f;
#pragma unroll
    for (int j = 0; j < 2; ++j)
#pragma unroll
        for (int c = 0; c < 8; ++c)
            if (l == j * 32 + c) { lo = acc[j][2 * c]; hi = acc[j][2 * c + 1]; }
    unsigned pack = (unsigned)f2bf(2.0f * lo) | ((unsigned)f2bf(2.0f * hi) << 16);
    *(unsigned*)&t2[(size_t)(rb + (l >> 5)) * 64 + (l & 31) * 2] = pack;
}

// ---------------- main GEMM ------------------------------------------------
// 256x256 tile, BK=64, 8 waves (2x4), LDS 2 bufs x (A 32KB + B 32KB) = 128KB.
// Row = 128B = 8 slots of 16B. Swizzle: phys slot p of row r holds logical
// slot p ^ (r&7); achieved by pre-swizzling the gload SOURCE (dest linear).
__global__ __launch_bounds__(512, 2) void qlora_gemm(
        const u16* __restrict__ xb, const u16* __restrict__ Wb,
        const u16* __restrict__ t2, const u16* __restrict__ B2,
        float* __restrict__ out) {
    __shared__ u16 lds[2][32768];                 // 128 KB
    // XCD-aware bijective swizzle: 512 blocks = 8 XCDs x 64
    int bid = blockIdx.x;
    int swz = (bid & 7) * 64 + (bid >> 3);
    int bn = swz >> 5;                            // 0..15
    int bm = swz & 31;                            // 0..31
    const int tid = threadIdx.x, w = tid >> 6, l = tid & 63;
    const int wr = w >> 2, wc = w & 3;            // 2x4 wave grid, 128x64 per wave
    const int fr = l & 15, fq = l >> 4;
    const int s0 = fq ^ (fr & 7);                 // swizzled slot, kk=0
    // (kk=1 slot = s0 ^ 4)

    // ---- staging addresses: op o covers tile rows o*64 + w*8 + (l>>3) ----
    const int sw16 = ((l & 7) ^ ((l >> 3) & 7)) << 4;   // pre-swizzled src offset
    const int rl   = w * 8 + (l >> 3);                  // row within op-0 stripe
    const int rA0  = bm * 256 + rl;
    const int rB0  = bn * 256 + rl;
    char* ldsC = (char*)&lds[0][0];
    const int dst = w * 1024 + l * 16;            // + o*8192 (A), +32768 (B)

    // ---- fragment-read byte offsets (within a buffer) --------------------
    const int arow = (wr * 128 + fr) * 128;              // + i*2048 + slot*16
    const int brow = 32768 + (wc * 64 + fr) * 128;       // + j*2048 + slot*16

    f32x4 acc[8][4] = {};

    auto stage = [&](int kt, int buf) {           // 8 gloads: full 64KB tile
        char* base = ldsC + buf * 65536;
        if (kt < KT_MAIN) {
            size_t ko = (size_t)kt * 128;
#pragma unroll
            for (int o = 0; o < 4; ++o) {
                gload16((const char*)xb + ((size_t)(rA0 + o * 64) * 8192 + sw16) + ko,
                        base + dst + o * 8192);
                gload16((const char*)Wb + ((size_t)(rB0 + o * 64) * 8192 + sw16) + ko,
                        base + 32768 + dst + o * 8192);
            }
        } else {                                  // lora tile (offsets computed here,
#pragma unroll                                     //  keeps them out of the reg budget)
            for (int o = 0; o < 4; ++o) {
                gload16((const char*)t2 + ((size_t)(rA0 + o * 64) * 128 + sw16),
                        base + dst + o * 8192);
                gload16((const char*)B2 + ((size_t)(rB0 + o * 64) * 128 + sw16),
                        base + 32768 + dst + o * 8192);
            }
        }
    };

    // ---------------- prologue ----------------
    stage(0, 0);
    asm volatile("s_waitcnt vmcnt(0)" ::: "memory");
    __builtin_amdgcn_s_barrier();
    asm volatile("" ::: "memory");

    bf16x8 a0[8], b0[4], a1[8], b1[4];
#pragma unroll
    for (int j = 0; j < 4; ++j)
        b0[j] = *(const bf16x8*)(ldsC + brow + j * 2048 + s0 * 16);
#pragma unroll
    for (int i = 0; i < 8; ++i)
        a0[i] = *(const bf16x8*)(ldsC + arow + i * 2048 + s0 * 16);

    for (int t = 0; t < NT; ++t) {
        const char* cb = ldsC + (t & 1) * 65536;

        // (1) kk1 frag reads — drain under kk0 MFMA
#pragma unroll
        for (int j = 0; j < 4; ++j)
            b1[j] = *(const bf16x8*)(cb + brow + j * 2048 + (s0 ^ 4) * 16);
#pragma unroll
        for (int i = 0; i < 8; ++i)
            a1[i] = *(const bf16x8*)(cb + arow + i * 2048 + (s0 ^ 4) * 16);
        // (2) next-tile staging — lands under this tile's compute
        if (t + 1 < NT) stage(t + 1, (t + 1) & 1);
        __builtin_amdgcn_sched_barrier(0);

        // (3) MFMA kk0 (compiler auto-waits a0/b0, which are long-landed)
        __builtin_amdgcn_s_setprio(1);
#pragma unroll
        for (int i = 0; i < 8; ++i)
#pragma unroll
            for (int j = 0; j < 4; ++j)
                acc[i][j] = __builtin_amdgcn_mfma_f32_16x16x32_bf16(
                                a0[i], b0[j], acc[i][j], 0, 0, 0);
        __builtin_amdgcn_s_setprio(0);
        __builtin_amdgcn_sched_barrier(0);

        // (4) protocol: all my buf-reads drained + next tile fully staged,
        //     then block-wide rendezvous (one barrier per K-tile)
        asm volatile("s_waitcnt lgkmcnt(0)" ::: "memory");
        asm volatile("s_waitcnt vmcnt(0)" ::: "memory");
        __builtin_amdgcn_s_barrier();
        asm volatile("" ::: "memory");

        // (5) next-tile kk0 frag reads — drain under kk1 MFMA
        if (t + 1 < NT) {
            const char* nb = ldsC + ((t + 1) & 1) * 65536;
#pragma unroll
            for (int j = 0; j < 4; ++j)
                b0[j] = *(const bf16x8*)(nb + brow + j * 2048 + s0 * 16);
#pragma unroll
            for (int i = 0; i < 8; ++i)
                a0[i] = *(const bf16x8*)(nb + arow + i * 2048 + s0 * 16);
        }
        __builtin_amdgcn_sched_barrier(0);

        // (6) MFMA kk1
        __builtin_amdgcn_s_setprio(1);
#pragma unroll
        for (int i = 0; i < 8; ++i)
#pragma unroll
            for (int j = 0; j < 4; ++j)
                acc[i][j] = __builtin_amdgcn_mfma_f32_16x16x32_bf16(
                                a1[i], b1[j], acc[i][j], 0, 0, 0);
        __builtin_amdgcn_s_setprio(0);
        __builtin_amdgcn_sched_barrier(0);
    }

    // epilogue: C/D layout col=lane&15, row=(lane>>4)*4+reg  [validated]
    float* obase = out + (size_t)(bm * 256 + wr * 128 + fq * 4) * N_DIM
                       + bn * 256 + wc * 64 + fr;
#pragma unroll
    for (int i = 0; i < 8; ++i)
#pragma unroll
        for (int j = 0; j < 4; ++j)
#pragma unroll
            for (int r = 0; r < 4; ++r)
                obase[(size_t)(i * 16 + r) * N_DIM + j * 16] = acc[i][j][r];
}

extern "C" void kernel_launch(void* const* d_in, const int* in_sizes, int n_in,
                              void* d_out, int out_size, void* d_ws, size_t ws_size,
                              hipStream_t stream) {
    const float* x      = (const float*)d_in[0];
    const int*   qw     = (const int*)d_in[1];
    const float* scales = (const float*)d_in[2];
    const float* lora_A = (const float*)d_in[3];
    const float* lora_B = (const float*)d_in[4];
    float* out = (float*)d_out;

    char* ws = (char*)d_ws;
    u16* xb = (u16*)(ws);                       // 8192*4096*2 = 67,108,864 B
    u16* Wb = (u16*)(ws + 67108864);            // 4096*4096*2 = 33,554,432 B
    u16* t2 = (u16*)(ws + 100663296);           // 8192*64*2   =  1,048,576 B
    u16* B2 = (u16*)(ws + 101711872);           // 4096*64*2   =    524,288 B

    wprep_kernel<<<8192, 256, 0, stream>>>(qw, scales, Wb);
    bprep_kernel<<<1024, 256, 0, stream>>>(lora_B, B2);
    xprep_kernel<<<1024, 256, 0, stream>>>(x, lora_A, xb, t2);
    qlora_gemm<<<dim3(512), 512, 0, stream>>>(xb, Wb, t2, B2, out);
}